// Round 8
// baseline (2128.021 us; speedup 1.0000x reference)
//
#include <hip/hip_runtime.h>
#include <stdint.h>

// IndexFlatIP top-k: sims = Q[512,512] @ X[262144,512]^T, per-row top-10
// indices (desc, ties -> lower index). Output int32 [512,10].
//
// Round 8: round-7 deep pipeline with COALESCED staging, no Xh materialization.
//  qprep: Q fp32 -> f16 RTZ granules (A-tile order), 512 KB, L2-resident.
//  p1   : BM=128 BN=128 BK=32, 4 waves (64x64 wave tile). A via glds (3 LDS
//         bufs), B reg-staged from fp32 X (3 static reg sets, cvt_pkrtz),
//         counted vmcnt(12)/(10) + raw s_barrier: 2-step slack for B (HBM),
//         1-step for A (L2). 48.7 KB LDS -> 3 blocks/CU. Fused per-row top-6
//         per 1024-col chunk. p2: pivot filter + exact fp32 rescore (verified).
#define B_Q   512
#define N_IDX 262144
#define D_DIM 512
#define TOPK  10
#define CAND  6

constexpr int CHUNKS = 256;          // candidate chunks (1024 cols each)
constexpr int NR = N_IDX / CHUNKS;   // 1024
constexpr int BM = 128, BN = 128, BK = 32;
constexpr int ITERS = (NR / BN) * (D_DIM / BK);   // 8 nt * 16 kt = 128
constexpr int NCAND = CHUNKS * CAND; // 1536
constexpr int CS_STRIDE = 17;

typedef _Float16 half8 __attribute__((ext_vector_type(8)));
typedef float    f32x4 __attribute__((ext_vector_type(4)));

__device__ __forceinline__ unsigned int pk16(float a, float b)
{
    return __builtin_bit_cast(unsigned int, __builtin_amdgcn_cvt_pkrtz(a, b));
}

__device__ __forceinline__ void glds16(const void* g, char* lds)
{
    __builtin_amdgcn_global_load_lds(
        (const __attribute__((address_space(1))) void*)g,
        (__attribute__((address_space(3))) void*)lds, 16, 0, 0);
}

// ------------------------------------------------------------------ qprep --
// A-tile granule order: tile (qt 0..3, kt 0..15), granule g = koct*128 + row,
// uint4 index = (qt*16+kt)*512 + g. Source granule n: row-major over Q.
__global__ __launch_bounds__(256)
void qprep(const float* __restrict__ Q, uint4* __restrict__ Qsw4)
{
    const int n = blockIdx.x * 256 + threadIdx.x;   // 32768 granules
    const float4 p0 = reinterpret_cast<const float4*>(Q)[n * 2];
    const float4 p1 = reinterpret_cast<const float4*>(Q)[n * 2 + 1];
    uint4 u;
    u.x = pk16(p0.x, p0.y);
    u.y = pk16(p0.z, p0.w);
    u.z = pk16(p1.x, p1.y);
    u.w = pk16(p1.z, p1.w);
    const int rowg = n >> 6, oct = n & 63;
    const int kt = oct >> 2, koct = oct & 3;
    const int qt = rowg >> 7, row = rowg & 127;
    Qsw4[(qt * 16 + kt) * 512 + koct * 128 + row] = u;
}

// --------------------------------------------------------------------- p1 --
// Grid 1024 (qt = bx&3 fast, chunk = bx>>2), block 256 = 4 waves (2M x 2N).
// LDS 49664 B: Abuf[3] 8K @0/8K/16K, Bbuf[2] 8K @24K/32K, Cs 128x17 @40960.
__global__ __launch_bounds__(256, 3)
void faiss_p1(const uint4* __restrict__ Qsw4, const float* __restrict__ X,
              float* __restrict__ cand_v, int* __restrict__ cand_i)
{
    __shared__ __align__(16) char smem[49664];
    float* Cs = (float*)(smem + 40960);

    const int tid  = threadIdx.x;
    const int lane = tid & 63;
    const int w    = tid >> 6;      // 0..3
    const int wm   = w >> 1;        // M half
    const int wn   = w & 1;         // N half
    const int qt    = blockIdx.x & 3;
    const int chunk = blockIdx.x >> 2;

    // A: wave w stages granules w*128 + i*64 + lane of tile (qt, kt)
    const uint4* aTile = Qsw4 + qt * (16 * 512) + w * 128 + lane;
    const int aDst = (w * 128) * 16;               // wave-uniform bytes

    // B: thread t -> col = t>>1, k-half kh = t&1 (16 fp32 = 64 B contiguous)
    const int bcol = tid >> 1, bkh = tid & 1;
    const float* Xb = X + (size_t)(chunk * NR + bcol) * D_DIM + bkh * 16;
    const int bD0 = (bkh * 256 + bcol) * 16;       // granule 2*kh
    const int bD1 = bD0 + 2048;                    // granule 2*kh+1

    int a_off[4], b_off[4];
#pragma unroll
    for (int i = 0; i < 4; ++i) {
        a_off[i] = ((lane >> 4) * 128 + wm * 64 + i * 16 + (lane & 15)) * 16;
        b_off[i] = ((lane >> 4) * 128 + wn * 64 + i * 16 + (lane & 15)) * 16;
    }

    float topv[CAND]; int topi[CAND];
#pragma unroll
    for (int j = 0; j < CAND; ++j) { topv[j] = -3.0e38f; topi[j] = 0; }

    f32x4 acc[4][4];
#pragma unroll
    for (int mi = 0; mi < 4; ++mi)
#pragma unroll
        for (int ni = 0; ni < 4; ++ni) acc[mi][ni] = (f32x4)0.0f;

    // 3 static B register sets (rule #20: no runtime indexing)
    float4 b0[4], b1[4], b2[4];

#define ISSUE_A(J)  do {                                                    \
        const uint4* _s = aTile + ((J) & 15) * 512;                         \
        char* _d = smem + ((J) % 3) * 8192;                                 \
        glds16(_s,        _d + aDst);                                       \
        glds16(_s + 64,   _d + aDst + 1024);                                \
    } while (0)

#define ISSUE_B(J, SET)  do {                                               \
        const float* _p = Xb + (size_t)((J) >> 4) * (BN * D_DIM) + ((J) & 15) * 32; \
        SET[0] = *reinterpret_cast<const float4*>(_p);                      \
        SET[1] = *reinterpret_cast<const float4*>(_p + 4);                  \
        SET[2] = *reinterpret_cast<const float4*>(_p + 8);                  \
        SET[3] = *reinterpret_cast<const float4*>(_p + 12);                 \
    } while (0)

#define WRITE_B(J, SET)  do {                                               \
        char* _bb = smem + 24576 + ((J) & 1) * 8192;                        \
        uint4 _u0, _u1;                                                     \
        _u0.x = pk16(SET[0].x, SET[0].y); _u0.y = pk16(SET[0].z, SET[0].w); \
        _u0.z = pk16(SET[1].x, SET[1].y); _u0.w = pk16(SET[1].z, SET[1].w); \
        _u1.x = pk16(SET[2].x, SET[2].y); _u1.y = pk16(SET[2].z, SET[2].w); \
        _u1.z = pk16(SET[3].x, SET[3].y); _u1.w = pk16(SET[3].z, SET[3].w); \
        *(uint4*)(_bb + bD0) = _u0;                                         \
        *(uint4*)(_bb + bD1) = _u1;                                         \
    } while (0)

#define COMPUTE(J)  do {                                                    \
        const char* _ab = smem + ((J) % 3) * 8192;                          \
        const char* _bb = smem + 24576 + ((J) & 1) * 8192;                  \
        half8 _af[4], _bf[4];                                               \
        for (int _m = 0; _m < 4; ++_m)                                      \
            _af[_m] = *reinterpret_cast<const half8*>(_ab + a_off[_m]);     \
        for (int _n = 0; _n < 4; ++_n)                                      \
            _bf[_n] = *reinterpret_cast<const half8*>(_bb + b_off[_n]);     \
        for (int _m = 0; _m < 4; ++_m)                                      \
            for (int _n = 0; _n < 4; ++_n)                                  \
                acc[_m][_n] = __builtin_amdgcn_mfma_f32_16x16x32_f16(       \
                    _af[_m], _bf[_n], acc[_m][_n], 0, 0, 0);                \
    } while (0)

    auto epilogue = [&](int nt) {
        const int col0g = chunk * NR + nt * BN;
#pragma unroll
        for (int s = 0; s < 8; ++s) {
            if (wn == (s >> 2)) {
                const int ni = s & 3;
#pragma unroll
                for (int mi = 0; mi < 4; ++mi)
#pragma unroll
                    for (int r = 0; r < 4; ++r) {
                        const int row = wm * 64 + mi * 16 + (lane >> 4) * 4 + r;
                        Cs[row * CS_STRIDE + (lane & 15)] = acc[mi][ni][r];
                    }
            }
            asm volatile("s_waitcnt lgkmcnt(0)" ::: "memory");
            __builtin_amdgcn_s_barrier();
            {
                const int row = tid >> 1, hf = tid & 1;
                const int base = col0g + s * 16 + hf * 8;
                for (int c = 0; c < 8; ++c) {
                    const float v = Cs[row * CS_STRIDE + hf * 8 + c];
                    const int id = base + c;
                    if (v > topv[CAND - 1] ||
                        (v == topv[CAND - 1] && id < topi[CAND - 1])) {
                        topv[CAND - 1] = v; topi[CAND - 1] = id;
#pragma unroll
                        for (int t = CAND - 1; t > 0; --t) {
                            const bool gt = topv[t] > topv[t - 1] ||
                                (topv[t] == topv[t - 1] && topi[t] < topi[t - 1]);
                            if (gt) {
                                const float tv = topv[t]; topv[t] = topv[t - 1]; topv[t - 1] = tv;
                                const int   ti = topi[t]; topi[t] = topi[t - 1]; topi[t - 1] = ti;
                            }
                        }
                    }
                }
            }
            asm volatile("s_waitcnt lgkmcnt(0)" ::: "memory");
            __builtin_amdgcn_s_barrier();
        }
#pragma unroll
        for (int mi = 0; mi < 4; ++mi)
#pragma unroll
            for (int ni = 0; ni < 4; ++ni) acc[mi][ni] = (f32x4)0.0f;
    };

    // STEP(J, Su, Sw): issue A(J+2), B(J+3)->set Su(=J%3); compute(J);
    // vmcnt(12) -> B(J+1) done; write set Sw(=(J+1)%3); vmcnt(10) -> A(J+1).
#define STEP(J, SU, SW)  do {                                               \
        ISSUE_A((J) + 2);                                                   \
        __builtin_amdgcn_sched_barrier(0);                                  \
        ISSUE_B((J) + 3, SU);                                               \
        __builtin_amdgcn_sched_barrier(0);                                  \
        COMPUTE(J);                                                         \
        __builtin_amdgcn_sched_barrier(0);                                  \
        asm volatile("s_waitcnt vmcnt(12)" ::: "memory");                   \
        WRITE_B((J) + 1, SW);                                               \
        asm volatile("s_waitcnt vmcnt(10) lgkmcnt(0)" ::: "memory");        \
        __builtin_amdgcn_s_barrier();                                       \
        if (((J) & 15) == 15) epilogue((J) >> 4);                           \
    } while (0)

    // prologue: Abuf0+Bbuf0 ready; queue = [B1:4, A1:2, B2:4]
    ISSUE_A(0);
    __builtin_amdgcn_sched_barrier(0);
    ISSUE_B(0, b0);
    __builtin_amdgcn_sched_barrier(0);
    asm volatile("s_waitcnt vmcnt(0)" ::: "memory");
    WRITE_B(0, b0);
    ISSUE_B(1, b1);
    __builtin_amdgcn_sched_barrier(0);
    ISSUE_A(1);
    __builtin_amdgcn_sched_barrier(0);
    ISSUE_B(2, b2);
    __builtin_amdgcn_sched_barrier(0);
    asm volatile("s_waitcnt lgkmcnt(0)" ::: "memory");
    __builtin_amdgcn_s_barrier();

    // uniform steps j = 0..122 (41 x unroll-3), then j = 123, 124
    for (int base = 0; base < 123; base += 3) {
        STEP(base + 0, b0, b1);
        STEP(base + 1, b1, b2);
        STEP(base + 2, b2, b0);
    }
    STEP(123, b0, b1);
    STEP(124, b1, b2);

    // tail j = 125,126,127
    ISSUE_A(127);
    __builtin_amdgcn_sched_barrier(0);
    COMPUTE(125);
    __builtin_amdgcn_sched_barrier(0);
    asm volatile("s_waitcnt vmcnt(8)" ::: "memory");
    WRITE_B(126, b0);
    asm volatile("s_waitcnt vmcnt(6) lgkmcnt(0)" ::: "memory");
    __builtin_amdgcn_s_barrier();

    COMPUTE(126);
    __builtin_amdgcn_sched_barrier(0);
    asm volatile("s_waitcnt vmcnt(2)" ::: "memory");
    WRITE_B(127, b1);
    asm volatile("s_waitcnt vmcnt(0) lgkmcnt(0)" ::: "memory");
    __builtin_amdgcn_s_barrier();

    COMPUTE(127);
    __builtin_amdgcn_sched_barrier(0);
    asm volatile("s_waitcnt lgkmcnt(0)" ::: "memory");
    __builtin_amdgcn_s_barrier();
    epilogue(7);

    // merge even/odd half-row scans, emit top-6
    float ov[CAND]; int oi[CAND];
#pragma unroll
    for (int j = 0; j < CAND; ++j) {
        ov[j] = __shfl_xor(topv[j], 1);
        oi[j] = __shfl_xor(topi[j], 1);
    }
    if ((tid & 1) == 0) {
        float mv[CAND]; int mx[CAND];
        int a = 0, b = 0;
#pragma unroll
        for (int t = 0; t < CAND; ++t) {
            const bool ta = (b >= CAND) ||
                (a < CAND && (topv[a] > ov[b] ||
                              (topv[a] == ov[b] && topi[a] < oi[b])));
            mv[t] = ta ? topv[a] : ov[b];
            mx[t] = ta ? topi[a] : oi[b];
            if (ta) ++a; else ++b;
        }
        const int rowg = qt * BM + (tid >> 1);
        const size_t base = ((size_t)rowg * CHUNKS + chunk) * CAND;
#pragma unroll
        for (int t = 0; t < CAND; ++t) {
            cand_v[base + t] = mv[t];
            cand_i[base + t] = mx[t];
        }
    }
#undef STEP
#undef COMPUTE
#undef WRITE_B
#undef ISSUE_B
#undef ISSUE_A
}

// --------------------------------------------------------------------- p2 --
// One block per row. Pivot = 24th-largest chunk-head under (v desc, idx asc)
// => pool {e >= pivot} provably contains the f16-top-24 => true top-10.
// Exact fp32 rescore of the pool from original Q,X; deterministic rank.
__global__ __launch_bounds__(256)
void faiss_p2(const float* __restrict__ cand_v, const int* __restrict__ cand_i,
              const float* __restrict__ Q, const float* __restrict__ X,
              int* __restrict__ out)
{
    __shared__ float vs[NCAND];
    __shared__ int   is[NCAND];
    __shared__ float qs[D_DIM];
    __shared__ int   Sidx[NCAND];
    __shared__ float Sval[NCAND];
    __shared__ int   scount;
    __shared__ float pivV;
    __shared__ int   pivI;

    const int row = blockIdx.x, tid = threadIdx.x;

    for (int i = tid; i < NCAND; i += 256) {
        vs[i] = cand_v[(size_t)row * NCAND + i];
        is[i] = cand_i[(size_t)row * NCAND + i];
    }
    if (tid < 128)
        ((float4*)qs)[tid] = ((const float4*)(Q + (size_t)row * D_DIM))[tid];
    if (tid == 0) scount = 0;
    __syncthreads();

    {
        const float h = vs[tid * CAND];
        const int  hid = is[tid * CAND];
        int r = 0;
        for (int j = 0; j < CHUNKS; ++j) {
            const float vj = vs[j * CAND];
            r += (vj > h) || (vj == h && is[j * CAND] < hid);
        }
        if (r == 23) { pivV = h; pivI = hid; }
    }
    __syncthreads();

    const float pv = pivV; const int pi = pivI;
    for (int i = tid; i < NCAND; i += 256) {
        const float v = vs[i]; const int id = is[i];
        if (v > pv || (v == pv && id <= pi)) {
            const int p = atomicAdd(&scount, 1);
            Sidx[p] = id;
        }
    }
    __syncthreads();
    const int nS = scount;

    const int wv = tid >> 6, ln = tid & 63;
    for (int si = wv; si < nS; si += 4) {
        const float* xr = X + (size_t)Sidx[si] * D_DIM + ln * 8;
        const float4 xa = *(const float4*)(xr);
        const float4 xb = *(const float4*)(xr + 4);
        const float* qp = qs + ln * 8;
        float s = 0.0f;
        s = fmaf(qp[0], xa.x, s); s = fmaf(qp[1], xa.y, s);
        s = fmaf(qp[2], xa.z, s); s = fmaf(qp[3], xa.w, s);
        s = fmaf(qp[4], xb.x, s); s = fmaf(qp[5], xb.y, s);
        s = fmaf(qp[6], xb.z, s); s = fmaf(qp[7], xb.w, s);
#pragma unroll
        for (int off = 32; off > 0; off >>= 1)
            s += __shfl_down(s, off);
        if (ln == 0) Sval[si] = s;
    }
    __syncthreads();

    for (int i = tid; i < nS; i += 256) {
        const float v = Sval[i]; const int id = Sidx[i];
        int r = 0;
        for (int j = 0; j < nS; ++j) {
            const float vj = Sval[j];
            r += (vj > v) || (vj == v && Sidx[j] < id);
        }
        if (r < TOPK) out[row * TOPK + r] = id;
    }
}

// ----------------------------------------------------------------- launch --
extern "C" void kernel_launch(void* const* d_in, const int* in_sizes, int n_in,
                              void* d_out, int out_size, void* d_ws, size_t ws_size,
                              hipStream_t stream)
{
    (void)in_sizes; (void)n_in; (void)out_size; (void)ws_size;
    const float* Q = (const float*)d_in[0];
    const float* X = (const float*)d_in[1];
    int* out = (int*)d_out;

    char* ws = (char*)d_ws;
    float* cand_v = (float*)ws;                              // 3.15 MB
    int*   cand_i = (int*)(ws + (size_t)B_Q * NCAND * 4);    // 3.15 MB
    uint4* Qsw4   = (uint4*)(ws + (size_t)B_Q * NCAND * 8);  // 512 KB

    qprep<<<dim3(128), dim3(256), 0, stream>>>(Q, Qsw4);
    faiss_p1<<<dim3(1024), dim3(256), 0, stream>>>(Qsw4, X, cand_v, cand_i);
    faiss_p2<<<dim3(B_Q), dim3(256), 0, stream>>>(cand_v, cand_i, Q, X, out);
}

// Round 9
// 2044.907 us; speedup vs baseline: 1.0406x; 1.0406x over previous
//
#include <hip/hip_runtime.h>
#include <stdint.h>

// IndexFlatIP top-k: sims = Q[512,512] @ X[262144,512]^T, per-row top-10
// indices (desc, ties -> lower index). Output int32 [512,10].
//
// Round 9 = round-8 skeleton, spill-free:
//  - __launch_bounds__(256) (NO min-waves cap: r8's (256,3) forced VGPR=80
//    and spilled ~50 regs -> 700 MB scratch writes).
//  - 2 B register sets (not 3): demand ~130 VGPR, fits 3 waves/SIMD.
//  - step order: compute -> vmcnt(4) -> writeB(j+1) -> barrier -> issue
//    A(j+2), B(j+3). FIFO at wait = [B(j+1):4, A(j+1):2, B(j+2):4] so
//    vmcnt(4) drains exactly B(j+1)+A(j+1); B has 2-step HBM slack.
//  - LDS 41.5 KB (A dbuf 2x8K, B dbuf 2x8K, Cs 128x17) -> 3 blocks/CU.
//  qprep / epilogue+scan / merge / p2: byte-level logic unchanged (verified
//  absmax=0 in rounds 5..8).
#define B_Q   512
#define N_IDX 262144
#define D_DIM 512
#define TOPK  10
#define CAND  6

constexpr int CHUNKS = 256;          // candidate chunks (1024 cols each)
constexpr int NR = N_IDX / CHUNKS;   // 1024
constexpr int BM = 128, BN = 128, BK = 32;
constexpr int ITERS = (NR / BN) * (D_DIM / BK);   // 8 nt * 16 kt = 128
constexpr int NCAND = CHUNKS * CAND; // 1536
constexpr int CS_STRIDE = 17;

typedef _Float16 half8 __attribute__((ext_vector_type(8)));
typedef float    f32x4 __attribute__((ext_vector_type(4)));

__device__ __forceinline__ unsigned int pk16(float a, float b)
{
    return __builtin_bit_cast(unsigned int, __builtin_amdgcn_cvt_pkrtz(a, b));
}

__device__ __forceinline__ void glds16(const void* g, char* lds)
{
    __builtin_amdgcn_global_load_lds(
        (const __attribute__((address_space(1))) void*)g,
        (__attribute__((address_space(3))) void*)lds, 16, 0, 0);
}

// ------------------------------------------------------------------ qprep --
// A-tile granule order: tile (qt 0..3, kt 0..15), granule g = koct*128 + row,
// uint4 index = (qt*16+kt)*512 + g.
__global__ __launch_bounds__(256)
void qprep(const float* __restrict__ Q, uint4* __restrict__ Qsw4)
{
    const int n = blockIdx.x * 256 + threadIdx.x;   // 32768 granules
    const float4 p0 = reinterpret_cast<const float4*>(Q)[n * 2];
    const float4 p1 = reinterpret_cast<const float4*>(Q)[n * 2 + 1];
    uint4 u;
    u.x = pk16(p0.x, p0.y);
    u.y = pk16(p0.z, p0.w);
    u.z = pk16(p1.x, p1.y);
    u.w = pk16(p1.z, p1.w);
    const int rowg = n >> 6, oct = n & 63;
    const int kt = oct >> 2, koct = oct & 3;
    const int qt = rowg >> 7, row = rowg & 127;
    Qsw4[(qt * 16 + kt) * 512 + koct * 128 + row] = u;
}

// --------------------------------------------------------------------- p1 --
// Grid 1024 (qt = bx&3 fast, chunk = bx>>2), block 256 = 4 waves (2M x 2N),
// wave tile 64x64. LDS 41472: Abuf[2] @0/@8K, Bbuf[2] @16K/@24K, Cs @32768.
__global__ __launch_bounds__(256)
void faiss_p1(const uint4* __restrict__ Qsw4, const float* __restrict__ X,
              float* __restrict__ cand_v, int* __restrict__ cand_i)
{
    __shared__ __align__(16) char smem[41472];
    float* Cs = (float*)(smem + 32768);

    const int tid  = threadIdx.x;
    const int lane = tid & 63;
    const int w    = tid >> 6;      // 0..3 (wave stages A k-octet w)
    const int wm   = w >> 1;        // M half
    const int wn   = w & 1;         // N half
    const int qt    = blockIdx.x & 3;
    const int chunk = blockIdx.x >> 2;

    // A: wave w stages granules w*128 + {0..63, 64..127} of tile (qt, kt)
    const uint4* aTile = Qsw4 + qt * (16 * 512) + w * 128 + lane;
    const int aDst = (w * 128) * 16;               // wave-uniform bytes

    // B: thread t -> col = t>>1, k-half kh = t&1 (16 fp32 = 64 B contiguous)
    const int bcol = tid >> 1, bkh = tid & 1;
    const float* Xb = X + (size_t)(chunk * NR + bcol) * D_DIM + bkh * 16;
    const int bD0 = (bkh * 256 + bcol) * 16;       // granule koct = 2*kh
    const int bD1 = bD0 + 2048;                    // koct = 2*kh+1

    int a_off[4], b_off[4];
#pragma unroll
    for (int i = 0; i < 4; ++i) {
        a_off[i] = ((lane >> 4) * 128 + wm * 64 + i * 16 + (lane & 15)) * 16;
        b_off[i] = ((lane >> 4) * 128 + wn * 64 + i * 16 + (lane & 15)) * 16;
    }

    float topv[CAND]; int topi[CAND];
#pragma unroll
    for (int j = 0; j < CAND; ++j) { topv[j] = -3.0e38f; topi[j] = 0; }

    f32x4 acc[4][4];
#pragma unroll
    for (int mi = 0; mi < 4; ++mi)
#pragma unroll
        for (int ni = 0; ni < 4; ++ni) acc[mi][ni] = (f32x4)0.0f;

    // 2 static B register sets: B(k) lives in set k&1
    float4 bE[4], bO[4];

#define ISSUE_A(J)  do {                                                    \
        const uint4* _s = aTile + ((J) & 15) * 512;                         \
        char* _d = smem + ((J) & 1) * 8192;                                 \
        glds16(_s,      _d + aDst);                                         \
        glds16(_s + 64, _d + aDst + 1024);                                  \
    } while (0)

#define ISSUE_B(J, SET)  do {                                               \
        const float* _p = Xb + (size_t)((J) >> 4) * (BN * D_DIM) + ((J) & 15) * 32; \
        SET[0] = *reinterpret_cast<const float4*>(_p);                      \
        SET[1] = *reinterpret_cast<const float4*>(_p + 4);                  \
        SET[2] = *reinterpret_cast<const float4*>(_p + 8);                  \
        SET[3] = *reinterpret_cast<const float4*>(_p + 12);                 \
    } while (0)

#define WRITE_B(J, SET)  do {                                               \
        char* _bb = smem + 16384 + ((J) & 1) * 8192;                        \
        uint4 _u0, _u1;                                                     \
        _u0.x = pk16(SET[0].x, SET[0].y); _u0.y = pk16(SET[0].z, SET[0].w); \
        _u0.z = pk16(SET[1].x, SET[1].y); _u0.w = pk16(SET[1].z, SET[1].w); \
        _u1.x = pk16(SET[2].x, SET[2].y); _u1.y = pk16(SET[2].z, SET[2].w); \
        _u1.z = pk16(SET[3].x, SET[3].y); _u1.w = pk16(SET[3].z, SET[3].w); \
        *(uint4*)(_bb + bD0) = _u0;                                         \
        *(uint4*)(_bb + bD1) = _u1;                                         \
    } while (0)

#define COMPUTE(J)  do {                                                    \
        const char* _ab = smem + ((J) & 1) * 8192;                          \
        const char* _bb = smem + 16384 + ((J) & 1) * 8192;                  \
        half8 _af[4], _bf[4];                                               \
        for (int _m = 0; _m < 4; ++_m)                                      \
            _af[_m] = *reinterpret_cast<const half8*>(_ab + a_off[_m]);     \
        for (int _n = 0; _n < 4; ++_n)                                      \
            _bf[_n] = *reinterpret_cast<const half8*>(_bb + b_off[_n]);     \
        __builtin_amdgcn_s_setprio(1);                                      \
        for (int _m = 0; _m < 4; ++_m)                                      \
            for (int _n = 0; _n < 4; ++_n)                                  \
                acc[_m][_n] = __builtin_amdgcn_mfma_f32_16x16x32_f16(       \
                    _af[_m], _bf[_n], acc[_m][_n], 0, 0, 0);                \
        __builtin_amdgcn_s_setprio(0);                                      \
    } while (0)

    auto epilogue = [&](int nt) {
        const int col0g = chunk * NR + nt * BN;
#pragma unroll
        for (int s = 0; s < 8; ++s) {
            if (wn == (s >> 2)) {
                const int ni = s & 3;
#pragma unroll
                for (int mi = 0; mi < 4; ++mi)
#pragma unroll
                    for (int r = 0; r < 4; ++r) {
                        const int row = wm * 64 + mi * 16 + (lane >> 4) * 4 + r;
                        Cs[row * CS_STRIDE + (lane & 15)] = acc[mi][ni][r];
                    }
            }
            asm volatile("s_waitcnt lgkmcnt(0)" ::: "memory");
            __builtin_amdgcn_s_barrier();
            {
                const int row = tid >> 1, hf = tid & 1;
                const int base = col0g + s * 16 + hf * 8;
                for (int c = 0; c < 8; ++c) {
                    const float v = Cs[row * CS_STRIDE + hf * 8 + c];
                    const int id = base + c;
                    if (v > topv[CAND - 1] ||
                        (v == topv[CAND - 1] && id < topi[CAND - 1])) {
                        topv[CAND - 1] = v; topi[CAND - 1] = id;
#pragma unroll
                        for (int t = CAND - 1; t > 0; --t) {
                            const bool gt = topv[t] > topv[t - 1] ||
                                (topv[t] == topv[t - 1] && topi[t] < topi[t - 1]);
                            if (gt) {
                                const float tv = topv[t]; topv[t] = topv[t - 1]; topv[t - 1] = tv;
                                const int   ti = topi[t]; topi[t] = topi[t - 1]; topi[t - 1] = ti;
                            }
                        }
                    }
                }
            }
            asm volatile("s_waitcnt lgkmcnt(0)" ::: "memory");
            __builtin_amdgcn_s_barrier();
        }
#pragma unroll
        for (int mi = 0; mi < 4; ++mi)
#pragma unroll
            for (int ni = 0; ni < 4; ++ni) acc[mi][ni] = (f32x4)0.0f;
    };

    // STEP(J, SET): SET = set((J+1)&1) used for both WRITE_B(J+1) and
    // ISSUE_B(J+3) (same parity). FIFO at the wait:
    // [B(J+1):4, A(J+1):2, B(J+2):4] -> vmcnt(4) drains B(J+1)+A(J+1).
#define STEP(J, SET)  do {                                                  \
        COMPUTE(J);                                                         \
        __builtin_amdgcn_sched_barrier(0);                                  \
        asm volatile("s_waitcnt vmcnt(4)" ::: "memory");                    \
        __builtin_amdgcn_sched_barrier(0);                                  \
        WRITE_B((J) + 1, SET);                                              \
        asm volatile("s_waitcnt lgkmcnt(0)" ::: "memory");                  \
        __builtin_amdgcn_s_barrier();                                       \
        ISSUE_A((J) + 2);                                                   \
        __builtin_amdgcn_sched_barrier(0);                                  \
        ISSUE_B((J) + 3, SET);                                              \
        __builtin_amdgcn_sched_barrier(0);                                  \
        if (((J) & 15) == 15) epilogue((J) >> 4);                           \
    } while (0)

    // prologue -> steady entry for j=0: LDS buf0 = A(0),B(0);
    // FIFO = [B(1):4, A(1):2, B(2):4]
    ISSUE_A(0);
    __builtin_amdgcn_sched_barrier(0);
    ISSUE_B(0, bE);
    __builtin_amdgcn_sched_barrier(0);
    asm volatile("s_waitcnt vmcnt(0)" ::: "memory");
    __builtin_amdgcn_sched_barrier(0);
    WRITE_B(0, bE);
    ISSUE_B(1, bO);
    __builtin_amdgcn_sched_barrier(0);
    ISSUE_A(1);
    __builtin_amdgcn_sched_barrier(0);
    ISSUE_B(2, bE);
    __builtin_amdgcn_sched_barrier(0);
    asm volatile("s_waitcnt lgkmcnt(0)" ::: "memory");
    __builtin_amdgcn_s_barrier();

    // uniform steps j = 0..123 (62 x unroll-2), then 124
    for (int j = 0; j < 124; j += 2) {
        STEP(j,     bO);    // B(j+1)->set1, B(j+3)->set1
        STEP(j + 1, bE);    // B(j+2)->set0, B(j+4)->set0
    }
    STEP(124, bO);          // WRITE_B(125), ISSUE_A(126), ISSUE_B(127)->bO

    // j=125: full entry FIFO [B(126),A(126),B(127)]; no B(128)
    COMPUTE(125);
    __builtin_amdgcn_sched_barrier(0);
    asm volatile("s_waitcnt vmcnt(4)" ::: "memory");
    __builtin_amdgcn_sched_barrier(0);
    WRITE_B(126, bE);
    asm volatile("s_waitcnt lgkmcnt(0)" ::: "memory");
    __builtin_amdgcn_s_barrier();
    ISSUE_A(127);
    __builtin_amdgcn_sched_barrier(0);

    // j=126: FIFO [B(127):4, A(127):2]
    COMPUTE(126);
    __builtin_amdgcn_sched_barrier(0);
    asm volatile("s_waitcnt vmcnt(0)" ::: "memory");
    __builtin_amdgcn_sched_barrier(0);
    WRITE_B(127, bO);
    asm volatile("s_waitcnt lgkmcnt(0)" ::: "memory");
    __builtin_amdgcn_s_barrier();

    // j=127
    COMPUTE(127);
    asm volatile("s_waitcnt lgkmcnt(0)" ::: "memory");
    __builtin_amdgcn_s_barrier();
    epilogue(7);

    // merge even/odd half-row scans, emit top-6
    float ov[CAND]; int oi[CAND];
#pragma unroll
    for (int j = 0; j < CAND; ++j) {
        ov[j] = __shfl_xor(topv[j], 1);
        oi[j] = __shfl_xor(topi[j], 1);
    }
    if ((tid & 1) == 0) {
        float mv[CAND]; int mx[CAND];
        int a = 0, b = 0;
#pragma unroll
        for (int t = 0; t < CAND; ++t) {
            const bool ta = (b >= CAND) ||
                (a < CAND && (topv[a] > ov[b] ||
                              (topv[a] == ov[b] && topi[a] < oi[b])));
            mv[t] = ta ? topv[a] : ov[b];
            mx[t] = ta ? topi[a] : oi[b];
            if (ta) ++a; else ++b;
        }
        const int rowg = qt * BM + (tid >> 1);
        const size_t base = ((size_t)rowg * CHUNKS + chunk) * CAND;
#pragma unroll
        for (int t = 0; t < CAND; ++t) {
            cand_v[base + t] = mv[t];
            cand_i[base + t] = mx[t];
        }
    }
#undef STEP
#undef COMPUTE
#undef WRITE_B
#undef ISSUE_B
#undef ISSUE_A
}

// --------------------------------------------------------------------- p2 --
// One block per row. Pivot = 24th-largest chunk-head under (v desc, idx asc)
// => pool {e >= pivot} provably contains the f16-top-24 => true top-10.
// Exact fp32 rescore of the pool from original Q,X; deterministic rank.
__global__ __launch_bounds__(256)
void faiss_p2(const float* __restrict__ cand_v, const int* __restrict__ cand_i,
              const float* __restrict__ Q, const float* __restrict__ X,
              int* __restrict__ out)
{
    __shared__ float vs[NCAND];
    __shared__ int   is[NCAND];
    __shared__ float qs[D_DIM];
    __shared__ int   Sidx[NCAND];
    __shared__ float Sval[NCAND];
    __shared__ int   scount;
    __shared__ float pivV;
    __shared__ int   pivI;

    const int row = blockIdx.x, tid = threadIdx.x;

    for (int i = tid; i < NCAND; i += 256) {
        vs[i] = cand_v[(size_t)row * NCAND + i];
        is[i] = cand_i[(size_t)row * NCAND + i];
    }
    if (tid < 128)
        ((float4*)qs)[tid] = ((const float4*)(Q + (size_t)row * D_DIM))[tid];
    if (tid == 0) scount = 0;
    __syncthreads();

    {
        const float h = vs[tid * CAND];
        const int  hid = is[tid * CAND];
        int r = 0;
        for (int j = 0; j < CHUNKS; ++j) {
            const float vj = vs[j * CAND];
            r += (vj > h) || (vj == h && is[j * CAND] < hid);
        }
        if (r == 23) { pivV = h; pivI = hid; }
    }
    __syncthreads();

    const float pv = pivV; const int pi = pivI;
    for (int i = tid; i < NCAND; i += 256) {
        const float v = vs[i]; const int id = is[i];
        if (v > pv || (v == pv && id <= pi)) {
            const int p = atomicAdd(&scount, 1);
            Sidx[p] = id;
        }
    }
    __syncthreads();
    const int nS = scount;

    const int wv = tid >> 6, ln = tid & 63;
    for (int si = wv; si < nS; si += 4) {
        const float* xr = X + (size_t)Sidx[si] * D_DIM + ln * 8;
        const float4 xa = *(const float4*)(xr);
        const float4 xb = *(const float4*)(xr + 4);
        const float* qp = qs + ln * 8;
        float s = 0.0f;
        s = fmaf(qp[0], xa.x, s); s = fmaf(qp[1], xa.y, s);
        s = fmaf(qp[2], xa.z, s); s = fmaf(qp[3], xa.w, s);
        s = fmaf(qp[4], xb.x, s); s = fmaf(qp[5], xb.y, s);
        s = fmaf(qp[6], xb.z, s); s = fmaf(qp[7], xb.w, s);
#pragma unroll
        for (int off = 32; off > 0; off >>= 1)
            s += __shfl_down(s, off);
        if (ln == 0) Sval[si] = s;
    }
    __syncthreads();

    for (int i = tid; i < nS; i += 256) {
        const float v = Sval[i]; const int id = Sidx[i];
        int r = 0;
        for (int j = 0; j < nS; ++j) {
            const float vj = Sval[j];
            r += (vj > v) || (vj == v && Sidx[j] < id);
        }
        if (r < TOPK) out[row * TOPK + r] = id;
    }
}

// ----------------------------------------------------------------- launch --
extern "C" void kernel_launch(void* const* d_in, const int* in_sizes, int n_in,
                              void* d_out, int out_size, void* d_ws, size_t ws_size,
                              hipStream_t stream)
{
    (void)in_sizes; (void)n_in; (void)out_size; (void)ws_size;
    const float* Q = (const float*)d_in[0];
    const float* X = (const float*)d_in[1];
    int* out = (int*)d_out;

    char* ws = (char*)d_ws;
    float* cand_v = (float*)ws;                              // 3.15 MB
    int*   cand_i = (int*)(ws + (size_t)B_Q * NCAND * 4);    // 3.15 MB
    uint4* Qsw4   = (uint4*)(ws + (size_t)B_Q * NCAND * 8);  // 512 KB

    qprep<<<dim3(128), dim3(256), 0, stream>>>(Q, Qsw4);
    faiss_p1<<<dim3(1024), dim3(256), 0, stream>>>(Qsw4, X, cand_v, cand_i);
    faiss_p2<<<dim3(B_Q), dim3(256), 0, stream>>>(cand_v, cand_i, Q, X, out);
}